// Round 8
// baseline (205.526 us; speedup 1.0000x reference)
//
#include <hip/hip_runtime.h>
#include <hip/hip_bf16.h>
#include <hip/hip_fp16.h>
#include <math.h>

#define BATCH 32
#define INC 1024
#define MIDC 256
#define SC 256
#define HW 784
#define ROWS 25088   // BATCH*HW
#define KSEL 196     // int(0.25 * 784)
#define BM1 112      // gemm1 rows/block; 112*7=784 -> blocks never span batches

typedef _Float16 f16;
typedef __attribute__((ext_vector_type(8))) _Float16 hfrag;  // 8 fp16 (4 VGPRs)
typedef __attribute__((ext_vector_type(4))) float f4;        // 4 fp32 acc

struct alignas(8) h4s { f16 x, y, z, w; };

__device__ inline float stanh_fast(float p) {
    // 1.7159*tanh(2p/3) = 1.7159*(1 - 2/(exp(4p/3)+1))
    float e = __expf(1.33333333f * p);
    return 1.7159f * (1.0f - 2.0f / (e + 1.0f));
}

// ---------------- fp32 -> fp16 weight convert (layout preserved) -----------
__global__ __launch_bounds__(256) void cvt_f16(const float* __restrict__ src,
                                               f16* __restrict__ dst, int n4) {
    int i = blockIdx.x * 256 + threadIdx.x;
    if (i >= n4) return;
    float4 v = ((const float4*)src)[i];
    h4s h = { (f16)v.x, (f16)v.y, (f16)v.z, (f16)v.w };
    ((h4s*)dst)[i] = h;
}

// ---------------- u[b][m] = Wq_b[m] + Uq·s ---------------------------------
__global__ __launch_bounds__(256) void calc_u(const float* __restrict__ s,
                                              const float* __restrict__ Uq_w,
                                              const float* __restrict__ Wq_b,
                                              float* __restrict__ u) {
    __shared__ float ssh[SC];
    int b = blockIdx.x, m = threadIdx.x;
    ssh[m] = s[b * SC + m];
    __syncthreads();
    float acc = Wq_b[m];
    const float* uq = Uq_w + (size_t)m * SC;
    #pragma unroll 8
    for (int i = 0; i < SC; ++i) acc += ssh[i] * uq[i];
    u[b * MIDC + m] = acc;
}

// ---------------- GEMM1 fused transpose: sig_t[R][m] = stanh(Wq·x + u) -----
// Block: 112 R x 256 mid, K=1024 (c), 32/step. x read directly [b][c][n]:
// coalesced fp32 tile -> LDS -> column-read (conflict-free) -> fp16 Bsm[n][k].
__global__ __launch_bounds__(256) void gemm1_fused(
    const float* __restrict__ x,   // [32][1024][784]
    const f16* __restrict__ Wq,    // [256][1024] fp16
    const float* __restrict__ u,   // [32][256]
    f16* __restrict__ S) {         // sig [25088][256]
    const int R0 = blockIdx.x * BM1;
    const int b  = R0 / HW;        // exact (112 | 784)
    const int n0 = R0 - b * HW;
    __shared__ f16   Asm[256][40];   // Wq tile: 256 m x 32 k
    __shared__ float Xf[32][116];    // x tile fp32: 32 c x 112 n (+pad, 16B-aligned rows)
    __shared__ f16   Bsm[BM1][40];   // transposed fp16: 112 n x 32 k

    const int t = threadIdx.x;
    const int lane = t & 63, w = t >> 6;
    const int wc = w * 64;           // each wave: 64 mids x all 112 R
    const int ln = lane & 15, kg = lane >> 4;

    // A staging: 1024 chunks of 8 fp16; 4/thread
    const int arow = t >> 2;             // +64*it? no: cid = t + it*256 -> row = cid>>2
    // x staging: 896 float4 chunks (32 rows x 28); up to 4/thread
    // transpose: 896 quads (112 n x 8 cq); up to 4/thread

    const float* xb = x + ((size_t)b * INC) * HW + n0;

    f4 acc[7][4];
    const f4 zero = {0.f, 0.f, 0.f, 0.f};
    #pragma unroll
    for (int i = 0; i < 7; ++i)
        #pragma unroll
        for (int j = 0; j < 4; ++j) acc[i][j] = zero;

    float4 rx[4];
    hfrag  rA[4];

    #define LOAD_TILES(K0)                                                     \
        _Pragma("unroll")                                                      \
        for (int it = 0; it < 4; ++it) {                                       \
            int cid = t + it * 256;                                            \
            rA[it] = *(const hfrag*)(Wq + (size_t)(cid >> 2) * INC + (K0) + (cid & 3) * 8); \
        }                                                                      \
        _Pragma("unroll")                                                      \
        for (int it = 0; it < 4; ++it) {                                       \
            int fid = t + it * 256;                                            \
            if (fid < 896) {                                                   \
                int cr = fid / 28, nc = (fid % 28) * 4;                        \
                rx[it] = *(const float4*)(xb + (size_t)((K0) + cr) * HW + nc); \
            }                                                                  \
        }

    LOAD_TILES(0)
    for (int k0 = 0; k0 < INC; k0 += 32) {
        // phase 1: dump regs to Asm / Xf
        #pragma unroll
        for (int it = 0; it < 4; ++it) {
            int cid = t + it * 256;
            *(hfrag*)&Asm[cid >> 2][(cid & 3) * 8] = rA[it];
        }
        #pragma unroll
        for (int it = 0; it < 4; ++it) {
            int fid = t + it * 256;
            if (fid < 896)
                *(float4*)&Xf[fid / 28][(fid % 28) * 4] = rx[it];
        }
        __syncthreads();
        // phase 2: transpose+convert Xf -> Bsm; issue next tile loads
        #pragma unroll
        for (int it = 0; it < 4; ++it) {
            int q = t + it * 256;
            if (q < 896) {
                int n = q % 112, cq = (q / 112) * 4;
                h4s hv = { (f16)Xf[cq + 0][n], (f16)Xf[cq + 1][n],
                           (f16)Xf[cq + 2][n], (f16)Xf[cq + 3][n] };
                *(h4s*)&Bsm[n][cq] = hv;
            }
        }
        if (k0 + 32 < INC) { LOAD_TILES(k0 + 32) }
        __syncthreads();
        // phase 3: fragments + MFMA
        hfrag bf[7];
        #pragma unroll
        for (int ri = 0; ri < 7; ++ri)
            bf[ri] = *(const hfrag*)&Bsm[ri * 16 + ln][kg * 8];
        #pragma unroll
        for (int mi = 0; mi < 4; ++mi) {
            hfrag a = *(const hfrag*)&Asm[wc + mi * 16 + ln][kg * 8];
            #pragma unroll
            for (int ri = 0; ri < 7; ++ri)
                acc[ri][mi] = __builtin_amdgcn_mfma_f32_16x16x32_f16(a, bf[ri], acc[ri][mi], 0, 0, 0);
        }
        __syncthreads();   // guard LDS reads vs next iteration's writes
    }
    #undef LOAD_TILES

    const float* ub = u + b * MIDC;
    #pragma unroll
    for (int ri = 0; ri < 7; ++ri) {
        int R = R0 + ri * 16 + ln;
        #pragma unroll
        for (int mi = 0; mi < 4; ++mi) {
            int mb = wc + mi * 16 + kg * 4;
            float uv[4];
            *(float4*)uv = *(const float4*)(ub + mb);
            h4s hv;
            hv.x = (f16)stanh_fast(acc[ri][mi][0] + uv[0]);
            hv.y = (f16)stanh_fast(acc[ri][mi][1] + uv[1]);
            hv.z = (f16)stanh_fast(acc[ri][mi][2] + uv[2]);
            hv.w = (f16)stanh_fast(acc[ri][mi][3] + uv[3]);
            *(h4s*)(S + (size_t)R * MIDC + mb) = hv;
        }
    }
}

// ---------------- GEMM2: alpha[b][c][n] = Ww·sig_t[R] + wb, R=(b,n) --------
__global__ __launch_bounds__(256) void gemm2_mfma(
    const f16* __restrict__ A,   // Ww [1024][256]
    const f16* __restrict__ B,   // sig [25088][256]
    const float* __restrict__ wb,
    float* __restrict__ aout) {
    const int R0 = blockIdx.x * 128;
    const int C0 = blockIdx.y * 128;
    __shared__ f16 Asm[128][40];
    __shared__ f16 Bsm[128][40];
    const int t = threadIdx.x;
    const int lane = t & 63, w = t >> 6;
    const int wc = (w >> 1) * 64;
    const int wr = (w & 1) * 64;
    const int ln = lane & 15, kg = lane >> 4;

    const int r0 = t >> 2, r1 = r0 + 64;
    const int kc = (t & 3) * 8;
    const size_t aoff0 = (size_t)(C0 + r0) * MIDC + kc;
    const size_t aoff1 = (size_t)(C0 + r1) * MIDC + kc;
    const size_t boff0 = (size_t)(R0 + r0) * MIDC + kc;
    const size_t boff1 = (size_t)(R0 + r1) * MIDC + kc;

    f4 acc[4][4];
    const f4 zero = {0.f, 0.f, 0.f, 0.f};
    #pragma unroll
    for (int i = 0; i < 4; ++i)
        #pragma unroll
        for (int j = 0; j < 4; ++j) acc[i][j] = zero;

    hfrag rA0, rA1, rB0, rB1;
    #define G2_LOAD(K0)                                   \
        rA0 = *(const hfrag*)(A + aoff0 + (K0));          \
        rA1 = *(const hfrag*)(A + aoff1 + (K0));          \
        rB0 = *(const hfrag*)(B + boff0 + (K0));          \
        rB1 = *(const hfrag*)(B + boff1 + (K0));

    G2_LOAD(0)
    for (int k0 = 0; k0 < MIDC; k0 += 32) {
        *(hfrag*)&Asm[r0][kc] = rA0;
        *(hfrag*)&Asm[r1][kc] = rA1;
        *(hfrag*)&Bsm[r0][kc] = rB0;
        *(hfrag*)&Bsm[r1][kc] = rB1;
        __syncthreads();
        if (k0 + 32 < MIDC) { G2_LOAD(k0 + 32) }
        hfrag bh[4];
        #pragma unroll
        for (int ni = 0; ni < 4; ++ni)
            bh[ni] = *(const hfrag*)&Bsm[wr + ni * 16 + ln][kg * 8];
        #pragma unroll
        for (int mi = 0; mi < 4; ++mi) {
            hfrag a = *(const hfrag*)&Asm[wc + mi * 16 + ln][kg * 8];
            #pragma unroll
            for (int ni = 0; ni < 4; ++ni)
                acc[mi][ni] = __builtin_amdgcn_mfma_f32_16x16x32_f16(a, bh[ni], acc[mi][ni], 0, 0, 0);
        }
        __syncthreads();
    }
    #undef G2_LOAD

    #pragma unroll
    for (int ni = 0; ni < 4; ++ni) {
        int R = R0 + wr + ni * 16 + ln;
        int b = R / HW;
        int n = R - b * HW;
        float* arow = aout + (size_t)b * INC * HW + n;
        #pragma unroll
        for (int mi = 0; mi < 4; ++mi) {
            int cb = C0 + wc + mi * 16 + kg * 4;
            float wv[4];
            *(float4*)wv = *(const float4*)(wb + cb);
            #pragma unroll
            for (int r = 0; r < 4; ++r)
                arow[(size_t)(cb + r) * HW] = acc[mi][ni][r] + wv[r];
        }
    }
}

// ---------------- per-(b,c) row: radix-select v3 (R6 version, reverted) ----
// Barrier-free (per-wave hist), float4 I/O, early-exit after any round when
// remaining rank hits bin boundary (kk==1 -> max of candidates, kk==hsel ->
// min of candidates). 16 value slots/lane; slot 3 only on lanes 0..3.
__global__ __launch_bounds__(256) void topk_softmax_reduce(const float* __restrict__ x,
                                                           float* __restrict__ out) {
    const int wid  = threadIdx.x >> 6;
    const int lane = threadIdx.x & 63;
    const int row  = blockIdx.x * 4 + wid;
    float* arow = out + BATCH * INC + (size_t)row * HW;
    const float* xrow = x + (size_t)row * HW;

    __shared__ int hist[4][4][264];   // [wave][subgroup][bin(+pad)]
    int* hp0 = &hist[wid][0][0];
    const int g = lane >> 4;

    const bool has3 = (lane < 4);
    float4 v4[4];
    uint32_t key[16];

    {   // vectorized load of the row (196 float4 chunks)
        const float4* ap = (const float4*)arow;
        v4[0] = ap[lane];
        v4[1] = ap[lane + 64];
        v4[2] = ap[lane + 128];
        v4[3] = has3 ? ap[192 + lane] : make_float4(0.f, 0.f, 0.f, 0.f);
    }
    const float* vv = (const float*)v4;
    #pragma unroll
    for (int i = 0; i < 16; ++i) {
        bool ok = (i < 12) | has3;
        uint32_t uu = __float_as_uint(vv[i]);
        uint32_t k = (uu & 0x80000000u) ? ~uu : (uu | 0x80000000u);
        key[i] = ok ? k : 0u;
    }

    int kk = KSEL;
    uint32_t prefix = 0;
    uint32_t thkey = 0;
    bool done = false;

    #pragma unroll
    for (int round = 0; round < 4; ++round) {
        if (!done) {
            const int shift = 24 - 8 * round;
            const int4 z4 = {0, 0, 0, 0};
            if (round == 0) {
                #pragma unroll
                for (int j = 0; j < 5; ++j) {
                    int idx = lane + 64 * j;
                    if (idx < 264) ((int4*)hp0)[idx] = z4;
                }
                #pragma unroll
                for (int i = 0; i < 16; ++i)
                    if (key[i]) atomicAdd(&hist[wid][g][key[i] >> 24], 1);
            } else {
                ((int4*)hp0)[lane] = z4;
                const uint32_t himask = 0xFFFFFFFFu << (shift + 8);
                #pragma unroll
                for (int i = 0; i < 16; ++i)
                    if ((key[i] & himask) == prefix)
                        atomicAdd(&hp0[(key[i] >> shift) & 255], 1);
            }

            int h0, h1, h2, h3;
            if (round == 0) {
                int4 c0 = *(const int4*)&hist[wid][0][4 * lane];
                int4 c1 = *(const int4*)&hist[wid][1][4 * lane];
                int4 c2 = *(const int4*)&hist[wid][2][4 * lane];
                int4 c3 = *(const int4*)&hist[wid][3][4 * lane];
                h0 = c0.x + c1.x + c2.x + c3.x;
                h1 = c0.y + c1.y + c2.y + c3.y;
                h2 = c0.z + c1.z + c2.z + c3.z;
                h3 = c0.w + c1.w + c2.w + c3.w;
            } else {
                int4 c = *(const int4*)&hp0[4 * lane];
                h0 = c.x; h1 = c.y; h2 = c.z; h3 = c.w;
            }
            int gsum = h0 + h1 + h2 + h3;
            int suf = gsum;
            #pragma unroll
            for (int off = 1; off < 64; off <<= 1) {
                int o = __shfl_down(suf, off, 64);
                suf += (lane + off < 64) ? o : 0;
            }
            int ex = suf - gsum;
            int cgt3 = ex, cgt2 = cgt3 + h3, cgt1 = cgt2 + h2, cgt0 = cgt1 + h1;
            int bsel = -1, cg = 0, hs = 0;
            if (cgt0 < kk && kk <= cgt0 + h0) { bsel = 4 * lane + 0; cg = cgt0; hs = h0; }
            if (cgt1 < kk && kk <= cgt1 + h1) { bsel = 4 * lane + 1; cg = cgt1; hs = h1; }
            if (cgt2 < kk && kk <= cgt2 + h2) { bsel = 4 * lane + 2; cg = cgt2; hs = h2; }
            if (cgt3 < kk && kk <= cgt3 + h3) { bsel = 4 * lane + 3; cg = cgt3; hs = h3; }
            unsigned long long m = __ballot(bsel >= 0);
            int src = (int)__ffsll((long long)m) - 1;
            bsel = __shfl(bsel, src, 64);
            cg   = __shfl(cg,   src, 64);
            hs   = __shfl(hs,   src, 64);
            kk -= cg;
            prefix |= ((uint32_t)bsel) << shift;

            if (shift == 0) {
                thkey = prefix;
                done = true;
            } else if (kk == 1 || kk == hs) {
                const uint32_t maskP = 0xFFFFFFFFu << shift;
                bool want_max = (kk == 1);
                uint32_t r = want_max ? 0u : 0xFFFFFFFFu;
                #pragma unroll
                for (int i = 0; i < 16; ++i) {
                    if ((key[i] & maskP) == prefix)
                        r = want_max ? (r > key[i] ? r : key[i])
                                     : (r < key[i] ? r : key[i]);
                }
                #pragma unroll
                for (int off = 32; off; off >>= 1) {
                    uint32_t o = __shfl_xor(r, off, 64);
                    r = want_max ? (r > o ? r : o) : (r < o ? r : o);
                }
                thkey = r;
                done = true;
            }
        }
    }

    uint32_t tu = (thkey & 0x80000000u) ? (thkey ^ 0x80000000u) : ~thkey;
    const float th = __uint_as_float(tu);

    // mask + max
    float* vw = (float*)v4;
    float mx = -INFINITY;
    #pragma unroll
    for (int i = 0; i < 16; ++i) {
        bool ok = (i < 12) | has3;
        float f = vw[i];
        f = (f < th) ? 0.0f : f;
        vw[i] = f;
        if (ok) mx = fmaxf(mx, f);
    }
    #pragma unroll
    for (int off = 32; off; off >>= 1) mx = fmaxf(mx, __shfl_xor(mx, off, 64));

    // exp + sum
    float sum = 0.f;
    #pragma unroll
    for (int i = 0; i < 16; ++i) {
        bool ok = (i < 12) | has3;
        float e = __expf(vw[i] - mx);
        vw[i] = e;
        sum += ok ? e : 0.f;
    }
    #pragma unroll
    for (int off = 32; off; off >>= 1) sum += __shfl_xor(sum, off, 64);
    float inv = 1.0f / sum;

    // normalize + store atten + weighted reduce against x
    float dot = 0.f;
    {
        float4* ap = (float4*)arow;
        const float4* xp = (const float4*)xrow;
        #pragma unroll
        for (int ci = 0; ci < 4; ++ci) {
            if (ci == 3 && !has3) break;
            int chunk = (ci < 3) ? (lane + 64 * ci) : (192 + lane);
            float4 a;
            a.x = vw[ci * 4 + 0] * inv;
            a.y = vw[ci * 4 + 1] * inv;
            a.z = vw[ci * 4 + 2] * inv;
            a.w = vw[ci * 4 + 3] * inv;
            ap[chunk] = a;
            float4 xl = xp[chunk];
            dot += xl.x * a.x + xl.y * a.y + xl.z * a.z + xl.w * a.w;
        }
    }
    #pragma unroll
    for (int off = 32; off; off >>= 1) dot += __shfl_xor(dot, off, 64);
    if (lane == 0) out[row] = dot;
}

extern "C" void kernel_launch(void* const* d_in, const int* in_sizes, int n_in,
                              void* d_out, int out_size, void* d_ws, size_t ws_size,
                              hipStream_t stream) {
    const float* x    = (const float*)d_in[0];
    const float* s    = (const float*)d_in[1];
    const float* Wq_w = (const float*)d_in[2];
    const float* Wq_b = (const float*)d_in[3];
    const float* Uq_w = (const float*)d_in[4];
    const float* w_w  = (const float*)d_in[5];
    const float* w_b  = (const float*)d_in[6];
    float* out = (float*)d_out;

    f16* sig  = (f16*)d_ws;                                   // [25088][256]
    f16* wq_h = sig + (size_t)ROWS * MIDC;                    // [256][1024]
    f16* ww_h = wq_h + MIDC * INC;                            // [1024][256]
    float* u  = (float*)(ww_h + INC * MIDC);                  // [32][256]
    float* alpha = out + BATCH * INC;                         // staged in atten slot

    cvt_f16<<<256, 256, 0, stream>>>(Wq_w, wq_h, MIDC * INC / 4);
    cvt_f16<<<256, 256, 0, stream>>>(w_w, ww_h, INC * MIDC / 4);
    calc_u<<<BATCH, 256, 0, stream>>>(s, Uq_w, Wq_b, u);
    gemm1_fused<<<ROWS / BM1, 256, 0, stream>>>(x, wq_h, u, sig);
    gemm2_mfma<<<dim3(ROWS / 128, 8), 256, 0, stream>>>(ww_h, sig, w_b, alpha);
    topk_softmax_reduce<<<BATCH * INC / 4, 256, 0, stream>>>(x, out);
}